// Round 9
// baseline (400.071 us; speedup 1.0000x reference)
//
#include <hip/hip_runtime.h>
#include <hip/hip_bf16.h>
#include <stdint.h>
#include <string.h>

#define NNODES 16384
#define GIN 256      // input feature dim
#define NG 64        // nodes per graph (N/G)
#define NGRAPH 256
#define FDIM 64      // per-head out dim
#define CDIM 512     // H*F

typedef __attribute__((ext_vector_type(8))) short bf16x8;
typedef __attribute__((ext_vector_type(4))) float f32x4;

__device__ __forceinline__ float bf2f(unsigned short u){
  union { unsigned int i; float f; } w; w.i = ((unsigned int)u) << 16; return w.f;
}

// unpack two bf16 packed in a uint to two floats
__device__ __forceinline__ void unpk(unsigned int u, float& lo, float& hi){
  union { unsigned int i; float f; } a, b;
  a.i = u << 16; b.i = u & 0xffff0000u;
  lo = a.f; hi = b.f;
}

union PK8 { __hip_bfloat16 h[8]; uint4 v; };

__device__ __forceinline__ void async16(const void* g, void* l){
  __builtin_amdgcn_global_load_lds(
      (const __attribute__((address_space(1))) unsigned int*)g,
      (__attribute__((address_space(3))) unsigned int*)l, 16, 0, 0);
}

// ---------- dtype detection: fp32 low-halves look like garbage bf16 ----------
__global__ void k_detect(const unsigned short* __restrict__ x, int* __restrict__ flag){
  int lane = threadIdx.x;  // 64 threads
  int bad = 0;
  #pragma unroll
  for (int j = 0; j < 4; j++){
    float f = bf2f(x[lane*4 + j]);
    if (!(fabsf(f) < 1e4f)) bad++;   // catches huge and NaN
  }
  #pragma unroll
  for (int o = 32; o; o >>= 1) bad += __shfl_down(bad, o);
  if (lane == 0) *flag = (bad > 16) ? 1 : 0;   // 1 = inputs are fp32
}

// ---------- small-vector conversion to fp32 (17 segments: att/b/gn/Wlin/blin) ----------
struct CArgs {
  const void* p[17];
  int cum[18];
};

__global__ void k_convert(CArgs a, const int* __restrict__ flag, float* __restrict__ dst, int total){
  int isf32 = *flag;
  for (int idx = blockIdx.x*blockDim.x + threadIdx.x; idx < total; idx += gridDim.x*blockDim.x){
    int seg = 0;
    while (idx >= a.cum[seg+1]) seg++;
    int off = idx - a.cum[seg];
    float v;
    if (isf32) v = ((const float*)a.p[seg])[off];
    else       v = bf2f(((const unsigned short*)a.p[seg])[off]);
    dst[idx] = v;
  }
}

// ---------- x -> bf16 (flag-dependent source dtype) + zero deg ----------
__global__ void k_xconv(const void* __restrict__ xin, const int* __restrict__ flag,
                        __hip_bfloat16* __restrict__ xbf, int* __restrict__ deg, int total){
  int isf32 = *flag;
  for (int idx = blockIdx.x*blockDim.x + threadIdx.x; idx < total; idx += gridDim.x*blockDim.x){
    if (idx < NNODES) deg[idx] = 0;
    float v;
    if (isf32) v = ((const float*)xin)[idx];
    else       v = bf2f(((const unsigned short*)xin)[idx]);
    xbf[idx] = __float2bfloat16(v);
  }
}

// ---------- merged transpose from RAW weights: 6 × (W[K x 512] -> Wt[512 x K] bf16) ----------
struct TArgs {
  const void* W[6];
  __hip_bfloat16* Wt[6];
  int K[6];
};

__global__ void k_transpose_all(TArgs t, const int* __restrict__ flag){
  int isf32 = *flag;
  int seg = blockIdx.z;
  int K = t.K[seg];
  int n0 = blockIdx.x*32, k0 = blockIdx.y*32;
  if (k0 >= K) return;
  const void* W = t.W[seg];
  __hip_bfloat16* Wt = t.Wt[seg];
  __shared__ float tl[32][33];
  for (int r = threadIdx.y; r < 32; r += 8){
    size_t idx = (size_t)(k0 + r)*CDIM + n0 + threadIdx.x;
    tl[r][threadIdx.x] = isf32 ? ((const float*)W)[idx] : bf2f(((const unsigned short*)W)[idx]);
  }
  __syncthreads();
  for (int r = threadIdx.y; r < 32; r += 8)
    Wt[(size_t)(n0 + r)*K + k0 + threadIdx.x] = __float2bfloat16(tl[threadIdx.x][r]);
}

// ---------- CSR build (by dst), payload = src node ----------
__global__ void k_count(const int* __restrict__ edst, int E, int* __restrict__ deg){
  int e = blockIdx.x*blockDim.x + threadIdx.x;
  if (e < E) atomicAdd(&deg[edst[e]], 1);
}

__global__ void k_scan(const int* __restrict__ deg, int* __restrict__ off, int* __restrict__ cur){
  __shared__ int ss[256];
  int t = threadIdx.x;
  int base = t * 64;
  int s = 0;
  for (int j = 0; j < 64; j++) s += deg[base + j];
  ss[t] = s;
  __syncthreads();
  for (int o = 1; o < 256; o <<= 1){
    int v = 0;
    if (t >= o) v = ss[t - o];
    __syncthreads();
    if (t >= o) ss[t] += v;
    __syncthreads();
  }
  int run = ss[t] - s;  // exclusive prefix
  for (int j = 0; j < 64; j++){
    int i = base + j;
    off[i] = run;
    cur[i] = run;
    run += deg[i];
  }
  if (t == 255) off[NNODES] = run;
}

__global__ void k_fill(const int* __restrict__ esrc, const int* __restrict__ edst, int E,
                       int* __restrict__ cur, int* __restrict__ srcs){
  int e = blockIdx.x*blockDim.x + threadIdx.x;
  if (e < E){
    int pos = atomicAdd(&cur[edst[e]], 1);
    srcs[pos] = esrc[e];
  }
}

// ---------- bf16 MFMA GEMM, 64x128 tile, BK=64, 4 waves (each 64x32), high occupancy ----------
// grid (N/64, CDIM/128, 2); LDS 24KB -> ~6 blocks/CU, 24 waves/CU (latency-bound regime).
__global__ __launch_bounds__(256) void k_gemm_mfma(
    const __hip_bfloat16* __restrict__ A,
    const __hip_bfloat16* __restrict__ Wtl, const __hip_bfloat16* __restrict__ Wtr,
    __hip_bfloat16* __restrict__ Cl, __hip_bfloat16* __restrict__ Cr, int K){
  const __hip_bfloat16* Wt = blockIdx.z ? Wtr : Wtl;
  __hip_bfloat16*       C  = blockIdx.z ? Cr  : Cl;
  __shared__ __align__(16) char As[8192];   // [c:8][m:64]  16B chunks
  __shared__ __align__(16) char Bs[16384];  // [c:8][n:128] 16B chunks
  int tid = threadIdx.x;
  int w = tid >> 6, lane = tid & 63;
  int row0 = blockIdx.x * 64, col0 = blockIdx.y * 128;
  int c = lane >> 4, l16 = lane & 15;

  f32x4 acc[4][2];
  #pragma unroll
  for (int i = 0; i < 4; i++)
    #pragma unroll
    for (int j = 0; j < 2; j++) acc[i][j] = (f32x4){0.f,0.f,0.f,0.f};

  for (int k0 = 0; k0 < K; k0 += 64){
    // stage 24 KB: 8 A-calls + 16 B-calls, 6 per wave, 1024B each
    #pragma unroll
    for (int t = 0; t < 6; t++){
      int call = t*4 + w;             // wave-uniform 0..23
      if (call < 8){
        const __hip_bfloat16* gp = A + (size_t)(row0 + lane)*K + k0 + call*8;
        async16(gp, As + call*1024);
      } else {
        int q = call - 8;
        int cc = q >> 1, half = q & 1;
        const __hip_bfloat16* gp = Wt + (size_t)(col0 + half*64 + lane)*K + k0 + cc*8;
        async16(gp, Bs + q*1024);
      }
    }
    __syncthreads();
    #pragma unroll
    for (int ko = 0; ko < 2; ko++){
      bf16x8 af[4], bfr[2];
      #pragma unroll
      for (int i = 0; i < 4; i++)
        af[i]  = *(const bf16x8*)(As + (ko*4 + c)*1024 + (i*16 + l16)*16);
      #pragma unroll
      for (int j = 0; j < 2; j++)
        bfr[j] = *(const bf16x8*)(Bs + (ko*4 + c)*2048 + (w*32 + j*16 + l16)*16);
      #pragma unroll
      for (int i = 0; i < 4; i++)
        #pragma unroll
        for (int j = 0; j < 2; j++)
          acc[i][j] = __builtin_amdgcn_mfma_f32_16x16x32_bf16(af[i], bfr[j], acc[i][j], 0, 0, 0);
    }
    __syncthreads();
  }

  int r4 = lane >> 4;
  #pragma unroll
  for (int i = 0; i < 4; i++)
    #pragma unroll
    for (int j = 0; j < 2; j++){
      __hip_bfloat16* cp = C + (size_t)(row0 + i*16 + r4*4)*CDIM + col0 + w*32 + j*16 + l16;
      #pragma unroll
      for (int r = 0; r < 4; r++)
        cp[(size_t)r*CDIM] = __float2bfloat16(acc[i][j][r]);
    }
}

// ---------- fused GATv2 edge phase, lane = (head, feature-octet), all-bf16 I/O ----------
// lane = h*8 + f8; lane owns channels c = lane*8 + j (j=0..7) -> contiguous 16B bf16 per lane.
template<int CONCAT>
__global__ __launch_bounds__(256) void k_fused_attn(
    const __hip_bfloat16* __restrict__ XL, const __hip_bfloat16* __restrict__ XR,
    const float* __restrict__ att,
    const int* __restrict__ off, const int* __restrict__ srcs,
    const float* __restrict__ bias, __hip_bfloat16* __restrict__ OUT){
  int wave = threadIdx.x >> 6, lane = threadIdx.x & 63;
  int d = blockIdx.x * 4 + wave;
  if (d >= NNODES) return;

  uint4 xru = *(const uint4*)((const char*)XR + ((size_t)d*CDIM + lane*8)*2);
  float xr[8];
  unpk(xru.x, xr[0], xr[1]); unpk(xru.y, xr[2], xr[3]);
  unpk(xru.z, xr[4], xr[5]); unpk(xru.w, xr[6], xr[7]);
  const float4* atp = (const float4*)(att + lane*8);
  float4 at0 = atp[0], at1 = atp[1];
  float at[8] = {at0.x, at0.y, at0.z, at0.w, at1.x, at1.y, at1.z, at1.w};

  float acc[8];
  #pragma unroll
  for (int j = 0; j < 8; j++) acc[j] = 0.f;
  float den = 0.f;

  int beg = off[d], end = off[d+1];

  auto leaky = [](float m){ return fmaxf(m, 0.2f*m); };

  for (int i = beg; i < end; i += 4){
    int n = end - i;                       // wave-uniform
    int s0 = srcs[i];
    int s1 = n > 1 ? srcs[i+1] : s0;
    int s2 = n > 2 ? srcs[i+2] : s0;
    int s3 = n > 3 ? srcs[i+3] : s0;
    uint4 rw[4];
    rw[0] = *(const uint4*)((const char*)XL + ((size_t)s0*CDIM + lane*8)*2);
    rw[1] = *(const uint4*)((const char*)XL + ((size_t)s1*CDIM + lane*8)*2);
    rw[2] = *(const uint4*)((const char*)XL + ((size_t)s2*CDIM + lane*8)*2);
    rw[3] = *(const uint4*)((const char*)XL + ((size_t)s3*CDIM + lane*8)*2);

    #pragma unroll
    for (int e = 0; e < 4; e++){
      if (e < n){                          // wave-uniform branch
        float xv[8];
        unpk(rw[e].x, xv[0], xv[1]);
        unpk(rw[e].y, xv[2], xv[3]);
        unpk(rw[e].z, xv[4], xv[5]);
        unpk(rw[e].w, xv[6], xv[7]);
        float v = 0.f;
        #pragma unroll
        for (int j = 0; j < 8; j++) v = fmaf(leaky(xv[j] + xr[j]), at[j], v);
        v += __shfl_xor(v, 1); v += __shfl_xor(v, 2); v += __shfl_xor(v, 4);
        float p = expf(v);
        den += p;
        #pragma unroll
        for (int j = 0; j < 8; j++) acc[j] = fmaf(p, xv[j], acc[j]);
      }
    }
  }

  float inv = 1.f / (den + 1e-16f);
  const float4* bp = (const float4*)(bias + (CONCAT ? lane*8 : (lane & 7)*8));

  if (CONCAT){
    float4 b0v = bp[0], b1v = bp[1];
    float bb[8] = {b0v.x, b0v.y, b0v.z, b0v.w, b1v.x, b1v.y, b1v.z, b1v.w};
    PK8 pk;
    #pragma unroll
    for (int j = 0; j < 8; j++)
      pk.h[j] = __float2bfloat16(acc[j]*inv + bb[j]);
    *(uint4*)((char*)OUT + ((size_t)d*CDIM + lane*8)*2) = pk.v;
  } else {
    float r[8];
    #pragma unroll
    for (int j = 0; j < 8; j++) r[j] = acc[j] * inv;
    #pragma unroll
    for (int o = 8; o < 64; o <<= 1)
      #pragma unroll
      for (int j = 0; j < 8; j++) r[j] += __shfl_xor(r[j], o);
    if (lane < 8){
      float4 b0v = bp[0], b1v = bp[1];
      float bb[8] = {b0v.x, b0v.y, b0v.z, b0v.w, b1v.x, b1v.y, b1v.z, b1v.w};
      PK8 pk;
      #pragma unroll
      for (int j = 0; j < 8; j++)
        pk.h[j] = __float2bfloat16(r[j]*0.125f + bb[j]);
      *(uint4*)((char*)OUT + ((size_t)d*FDIM + lane*8)*2) = pk.v;
    }
  }
}

// ---------- GraphNorm + ReLU, single pass: thread t caches its column in registers ----------
// block = graph g, blockDim = C; thread t owns column t across the graph's 64 rows.
__global__ void k_graphnorm_relu(const __hip_bfloat16* __restrict__ X, const float* __restrict__ w,
    const float* __restrict__ b, const float* __restrict__ ms,
    __hip_bfloat16* __restrict__ Y, int C){
  int g = blockIdx.x;
  int c = threadIdx.x;
  const __hip_bfloat16* xg = X + (size_t)g * NG * C + c;
  __hip_bfloat16* yg = Y + (size_t)g * NG * C + c;
  float v[NG];
  float s1 = 0.f, s2 = 0.f;
  #pragma unroll
  for (int i = 0; i < NG; i++){
    v[i] = __bfloat162float(xg[(size_t)i*C]);
    s1 += v[i]; s2 += v[i]*v[i];
  }
  float mean = s1 * (1.f/NG);
  float m = ms[c];
  float var = s2 * (1.f/NG) - 2.f*m*mean*mean + m*m*mean*mean;
  float inv = rsqrtf(var + 1e-5f);
  float ww = w[c], bb = b[c];
  #pragma unroll
  for (int i = 0; i < NG; i++){
    float y = fmaf(ww * (v[i] - m*mean), inv, bb);
    yg[(size_t)i*C] = __float2bfloat16(y > 0.f ? y : 0.f);
  }
}

// ---------- global mean pool + linear [64 -> 2], dtype-flag-aware output ----------
__global__ void k_pool_linear(const __hip_bfloat16* __restrict__ H, const float* __restrict__ Wlin,
    const float* __restrict__ blin, void* out, const int* __restrict__ flag){
  int g = blockIdx.x, c = threadIdx.x;  // 64 threads
  float s = 0.f;
  for (int i = 0; i < NG; i++) s += __bfloat162float(H[(long)(g*NG + i)*FDIM + c]);
  float pooled = s * (1.f/NG);
  float v0 = pooled * Wlin[c*2 + 0];
  float v1 = pooled * Wlin[c*2 + 1];
  #pragma unroll
  for (int o = 32; o; o >>= 1){ v0 += __shfl_down(v0, o); v1 += __shfl_down(v1, o); }
  if (c == 0){
    float o0 = v0 + blin[0], o1 = v1 + blin[1];
    if (*flag){
      ((float*)out)[g*2 + 0] = o0;
      ((float*)out)[g*2 + 1] = o1;
    } else {
      ((__hip_bfloat16*)out)[g*2 + 0] = __float2bfloat16(o0);
      ((__hip_bfloat16*)out)[g*2 + 1] = __float2bfloat16(o1);
    }
  }
}

extern "C" void kernel_launch(void* const* d_in, const int* in_sizes, int n_in,
                              void* d_out, int out_size, void* d_ws, size_t ws_size,
                              hipStream_t stream){
  const int N = NNODES;
  const int E = in_sizes[1];

  const int* esrc = (const int*)d_in[1];
  const int* edst = (const int*)d_in[2];

  // ---- workspace layout ----
  char* ws = (char*)d_ws;
  size_t cursor_b = 0;
  auto alloc = [&](size_t bytes)->char*{
    char* p = ws + cursor_b;
    cursor_b += (bytes + 255) & ~size_t(255);
    return p;
  };

  int* flag = (int*)alloc(256);

  // small segments only: att1,b1,gnw1,gnb1,gnm1, att2.., att3.., Wlin, blin
  static const int convIdx[17] = {6,7,8,9,10, 13,14,15,16,17, 20,21,22,23,24, 25,26};
  CArgs ca;
  int cums[18]; cums[0] = 0;
  for (int i = 0; i < 17; i++){
    ca.p[i] = d_in[convIdx[i]];
    cums[i+1] = cums[i] + in_sizes[convIdx[i]];
  }
  memcpy(ca.cum, cums, sizeof(cums));
  int totalConv = cums[17];

  float* conv = (float*)alloc((size_t)totalConv * 4);
  const float* fw[17];
  for (int i = 0; i < 17; i++) fw[i] = conv + cums[i];
  // fw map: 0:att1 1:b1 2:gnw1 3:gnb1 4:gnm1
  //         5:att2 6:b2 7:gnw2 8:gnb2 9:gnm2
  //         10:att3 11:b3 12:gnw3 13:gnb3 14:gnm3 15:Wlin 16:blin

  __hip_bfloat16* XLbf  = (__hip_bfloat16*)alloc((size_t)N * CDIM * 2);
  __hip_bfloat16* XRbf  = (__hip_bfloat16*)alloc((size_t)N * CDIM * 2);
  __hip_bfloat16* OUTbf = (__hip_bfloat16*)alloc((size_t)N * CDIM * 2);   // attn out, pre-norm
  __hip_bfloat16* OUT3  = (__hip_bfloat16*)alloc((size_t)N * FDIM * 2);
  __hip_bfloat16* HBbf  = (__hip_bfloat16*)alloc((size_t)N * CDIM * 2);
  __hip_bfloat16* xbf   = (__hip_bfloat16*)alloc((size_t)N * GIN * 2);
  __hip_bfloat16* Wt[6];
  Wt[0] = (__hip_bfloat16*)alloc((size_t)CDIM * GIN * 2);
  Wt[1] = (__hip_bfloat16*)alloc((size_t)CDIM * GIN * 2);
  Wt[2] = (__hip_bfloat16*)alloc((size_t)CDIM * CDIM * 2);
  Wt[3] = (__hip_bfloat16*)alloc((size_t)CDIM * CDIM * 2);
  Wt[4] = (__hip_bfloat16*)alloc((size_t)CDIM * CDIM * 2);
  Wt[5] = (__hip_bfloat16*)alloc((size_t)CDIM * CDIM * 2);
  int* deg  = (int*)alloc((size_t)N * 4);
  int* off  = (int*)alloc((size_t)(N + 1) * 4);
  int* cur  = (int*)alloc((size_t)N * 4);
  int* srcs = (int*)alloc((size_t)E * 4);

  // ---- dtype detect + convert (+ deg zero) ----
  k_detect<<<1, 64, 0, stream>>>((const unsigned short*)d_in[0], flag);
  k_convert<<<32, 256, 0, stream>>>(ca, flag, conv, totalConv);
  k_xconv<<<2048, 256, 0, stream>>>(d_in[0], flag, xbf, deg, N * GIN);
  {
    TArgs ta;
    const void* Ws[6] = {d_in[4], d_in[5], d_in[11], d_in[12], d_in[18], d_in[19]};
    const int   Ks[6] = {GIN, GIN, CDIM, CDIM, CDIM, CDIM};
    for (int i = 0; i < 6; i++){ ta.W[i] = Ws[i]; ta.Wt[i] = Wt[i]; ta.K[i] = Ks[i]; }
    k_transpose_all<<<dim3(CDIM/32, CDIM/32, 6), dim3(32, 8), 0, stream>>>(ta, flag);
  }

  // ---- CSR by dst (payload = src) ----
  k_count<<<(E + 255)/256, 256, 0, stream>>>(edst, E, deg);
  k_scan<<<1, 256, 0, stream>>>(deg, off, cur);
  k_fill<<<(E + 255)/256, 256, 0, stream>>>(esrc, edst, E, cur, srcs);

  // ---- 3 GATv2 + GraphNorm + ReLU layers ----
  const float* att_[3] = {fw[0],  fw[5],  fw[10]};
  const float* b_[3]   = {fw[1],  fw[6],  fw[11]};
  const float* gw_[3]  = {fw[2],  fw[7],  fw[12]};
  const float* gb_[3]  = {fw[3],  fw[8],  fw[13]};
  const float* gm_[3]  = {fw[4],  fw[9],  fw[14]};

  const __hip_bfloat16* inbuf = xbf;
  int K = GIN;
  for (int layer = 0; layer < 3; layer++){
    k_gemm_mfma<<<dim3(N/64, CDIM/128, 2), 256, 0, stream>>>(
        inbuf, Wt[layer*2], Wt[layer*2 + 1], XLbf, XRbf, K);
    if (layer < 2){
      k_fused_attn<1><<<N/4, 256, 0, stream>>>(XLbf, XRbf, att_[layer], off, srcs, b_[layer], OUTbf);
      k_graphnorm_relu<<<NGRAPH, CDIM, 0, stream>>>(OUTbf, gw_[layer], gb_[layer], gm_[layer], HBbf, CDIM);
    } else {
      k_fused_attn<0><<<N/4, 256, 0, stream>>>(XLbf, XRbf, att_[layer], off, srcs, b_[layer], OUT3);
      k_graphnorm_relu<<<NGRAPH, FDIM, 0, stream>>>(OUT3, gw_[layer], gb_[layer], gm_[layer], HBbf, FDIM);
    }
    inbuf = HBbf;
    K = CDIM;
  }

  // ---- pool + linear ----
  k_pool_linear<<<NGRAPH, 64, 0, stream>>>(HBbf, fw[15], fw[16], d_out, flag);
}

// Round 10
// 363.785 us; speedup vs baseline: 1.0997x; 1.0997x over previous
//
#include <hip/hip_runtime.h>
#include <hip/hip_bf16.h>
#include <stdint.h>
#include <string.h>

#define NNODES 16384
#define GIN 256      // input feature dim
#define NG 64        // nodes per graph (N/G)
#define NGRAPH 256
#define FDIM 64      // per-head out dim
#define CDIM 512     // H*F

typedef __attribute__((ext_vector_type(8))) short bf16x8;
typedef __attribute__((ext_vector_type(4))) float f32x4;

__device__ __forceinline__ float bf2f(unsigned short u){
  union { unsigned int i; float f; } w; w.i = ((unsigned int)u) << 16; return w.f;
}

// unpack two bf16 packed in a uint to two floats
__device__ __forceinline__ void unpk(unsigned int u, float& lo, float& hi){
  union { unsigned int i; float f; } a, b;
  a.i = u << 16; b.i = u & 0xffff0000u;
  lo = a.f; hi = b.f;
}

union PK8 { __hip_bfloat16 h[8]; uint4 v; };

__device__ __forceinline__ void async16(const void* g, void* l){
  __builtin_amdgcn_global_load_lds(
      (const __attribute__((address_space(1))) unsigned int*)g,
      (__attribute__((address_space(3))) unsigned int*)l, 16, 0, 0);
}

// ---------- dtype detection: fp32 low-halves look like garbage bf16 ----------
__global__ void k_detect(const unsigned short* __restrict__ x, int* __restrict__ flag){
  int lane = threadIdx.x;  // 64 threads
  int bad = 0;
  #pragma unroll
  for (int j = 0; j < 4; j++){
    float f = bf2f(x[lane*4 + j]);
    if (!(fabsf(f) < 1e4f)) bad++;   // catches huge and NaN
  }
  #pragma unroll
  for (int o = 32; o; o >>= 1) bad += __shfl_down(bad, o);
  if (lane == 0) *flag = (bad > 16) ? 1 : 0;   // 1 = inputs are fp32
}

// ---------- small-vector conversion to fp32 (17 segments: att/b/gn/Wlin/blin) ----------
struct CArgs {
  const void* p[17];
  int cum[18];
};

__global__ void k_convert(CArgs a, const int* __restrict__ flag, float* __restrict__ dst, int total){
  int isf32 = *flag;
  for (int idx = blockIdx.x*blockDim.x + threadIdx.x; idx < total; idx += gridDim.x*blockDim.x){
    int seg = 0;
    while (idx >= a.cum[seg+1]) seg++;
    int off = idx - a.cum[seg];
    float v;
    if (isf32) v = ((const float*)a.p[seg])[off];
    else       v = bf2f(((const unsigned short*)a.p[seg])[off]);
    dst[idx] = v;
  }
}

// ---------- x -> bf16 (flag-dependent source dtype) + zero deg ----------
__global__ void k_xconv(const void* __restrict__ xin, const int* __restrict__ flag,
                        __hip_bfloat16* __restrict__ xbf, int* __restrict__ deg, int total){
  int isf32 = *flag;
  for (int idx = blockIdx.x*blockDim.x + threadIdx.x; idx < total; idx += gridDim.x*blockDim.x){
    if (idx < NNODES) deg[idx] = 0;
    float v;
    if (isf32) v = ((const float*)xin)[idx];
    else       v = bf2f(((const unsigned short*)xin)[idx]);
    xbf[idx] = __float2bfloat16(v);
  }
}

// ---------- merged transpose from RAW weights: 6 × (W[K x 512] -> Wt[512 x K] bf16) ----------
struct TArgs {
  const void* W[6];
  __hip_bfloat16* Wt[6];
  int K[6];
};

__global__ void k_transpose_all(TArgs t, const int* __restrict__ flag){
  int isf32 = *flag;
  int seg = blockIdx.z;
  int K = t.K[seg];
  int n0 = blockIdx.x*32, k0 = blockIdx.y*32;
  if (k0 >= K) return;
  const void* W = t.W[seg];
  __hip_bfloat16* Wt = t.Wt[seg];
  __shared__ float tl[32][33];
  for (int r = threadIdx.y; r < 32; r += 8){
    size_t idx = (size_t)(k0 + r)*CDIM + n0 + threadIdx.x;
    tl[r][threadIdx.x] = isf32 ? ((const float*)W)[idx] : bf2f(((const unsigned short*)W)[idx]);
  }
  __syncthreads();
  for (int r = threadIdx.y; r < 32; r += 8)
    Wt[(size_t)(n0 + r)*K + k0 + threadIdx.x] = __float2bfloat16(tl[threadIdx.x][r]);
}

// ---------- CSR build (by dst), payload = src node ----------
__global__ void k_count(const int* __restrict__ edst, int E, int* __restrict__ deg){
  int e = blockIdx.x*blockDim.x + threadIdx.x;
  if (e < E) atomicAdd(&deg[edst[e]], 1);
}

__global__ void k_scan(const int* __restrict__ deg, int* __restrict__ off, int* __restrict__ cur){
  __shared__ int ss[256];
  int t = threadIdx.x;
  int base = t * 64;
  int s = 0;
  for (int j = 0; j < 64; j++) s += deg[base + j];
  ss[t] = s;
  __syncthreads();
  for (int o = 1; o < 256; o <<= 1){
    int v = 0;
    if (t >= o) v = ss[t - o];
    __syncthreads();
    if (t >= o) ss[t] += v;
    __syncthreads();
  }
  int run = ss[t] - s;  // exclusive prefix
  for (int j = 0; j < 64; j++){
    int i = base + j;
    off[i] = run;
    cur[i] = run;
    run += deg[i];
  }
  if (t == 255) off[NNODES] = run;
}

__global__ void k_fill(const int* __restrict__ esrc, const int* __restrict__ edst, int E,
                       int* __restrict__ cur, int* __restrict__ srcs){
  int e = blockIdx.x*blockDim.x + threadIdx.x;
  if (e < E){
    int pos = atomicAdd(&cur[edst[e]], 1);
    srcs[pos] = esrc[e];
  }
}

// ---------- bf16 MFMA GEMM, 128x128 tile, BK=64, double-buffered LDS prefetch ----------
// Per iter: ds_read all frags of tile k -> issue async stage of tile k+1 -> MFMAs -> barrier.
// The barrier drains the prefetch AFTER it overlapped the MFMA issue (stage>compute regime).
__global__ __launch_bounds__(256) void k_gemm_mfma(
    const __hip_bfloat16* __restrict__ A,
    const __hip_bfloat16* __restrict__ Wtl, const __hip_bfloat16* __restrict__ Wtr,
    __hip_bfloat16* __restrict__ Cl, __hip_bfloat16* __restrict__ Cr, int K){
  const __hip_bfloat16* Wt = blockIdx.z ? Wtr : Wtl;
  __hip_bfloat16*       C  = blockIdx.z ? Cr  : Cl;
  __shared__ __align__(16) char As[2][16384];  // [buf][c:8][m:128] 16B chunks (BK=64)
  __shared__ __align__(16) char Bs[2][16384];
  int tid = threadIdx.x;
  int w = tid >> 6, lane = tid & 63;
  int wm = (w >> 1) & 1, wn = w & 1;
  int row0 = blockIdx.x * 128, col0 = blockIdx.y * 128;
  int c = lane >> 4, l16 = lane & 15;

  f32x4 acc[4][4];
  #pragma unroll
  for (int i = 0; i < 4; i++)
    #pragma unroll
    for (int j = 0; j < 4; j++) acc[i][j] = (f32x4){0.f,0.f,0.f,0.f};

  auto stage = [&](int buf, int k0){
    #pragma unroll
    for (int t = 0; t < 8; t++){
      int call = t*4 + w;             // wave-uniform 0..31
      if (call < 16){
        int cc = call >> 1, half = call & 1;
        const __hip_bfloat16* gp = A + (size_t)(row0 + half*64 + lane)*K + k0 + cc*8;
        async16(gp, As[buf] + call*1024);
      } else {
        int q = call - 16;
        int cc = q >> 1, half = q & 1;
        const __hip_bfloat16* gp = Wt + (size_t)(col0 + half*64 + lane)*K + k0 + cc*8;
        async16(gp, Bs[buf] + q*1024);
      }
    }
  };

  stage(0, 0);
  __syncthreads();

  int nIter = K >> 6;
  for (int it = 0; it < nIter; it++){
    int cur = it & 1;
    // 1) pull tile-it fragments from LDS into registers
    bf16x8 af[2][4], bfr[2][4];
    #pragma unroll
    for (int ko = 0; ko < 2; ko++){
      #pragma unroll
      for (int i = 0; i < 4; i++)
        af[ko][i]  = *(const bf16x8*)(As[cur] + (ko*4 + c)*2048 + (wm*64 + i*16 + l16)*16);
      #pragma unroll
      for (int j = 0; j < 4; j++)
        bfr[ko][j] = *(const bf16x8*)(Bs[cur] + (ko*4 + c)*2048 + (wn*64 + j*16 + l16)*16);
    }
    // 2) issue async prefetch of tile it+1 (overlaps the MFMA burst below)
    if (it + 1 < nIter) stage(1 - cur, (it + 1) << 6);
    // 3) compute
    #pragma unroll
    for (int ko = 0; ko < 2; ko++)
      #pragma unroll
      for (int i = 0; i < 4; i++)
        #pragma unroll
        for (int j = 0; j < 4; j++)
          acc[i][j] = __builtin_amdgcn_mfma_f32_16x16x32_bf16(af[ko][i], bfr[ko][j], acc[i][j], 0, 0, 0);
    __syncthreads();
  }

  int r4 = lane >> 4;
  #pragma unroll
  for (int i = 0; i < 4; i++)
    #pragma unroll
    for (int j = 0; j < 4; j++){
      __hip_bfloat16* cp = C + (size_t)(row0 + wm*64 + i*16 + r4*4)*CDIM + col0 + wn*64 + j*16 + l16;
      #pragma unroll
      for (int r = 0; r < 4; r++)
        cp[(size_t)r*CDIM] = __float2bfloat16(acc[i][j][r]);
    }
}

// ---------- fused GATv2 edge phase, lane = (head, feature-octet), all-bf16 I/O ----------
// lane = h*8 + f8; lane owns channels c = lane*8 + j (j=0..7) -> contiguous 16B bf16 per lane.
template<int CONCAT>
__global__ __launch_bounds__(256) void k_fused_attn(
    const __hip_bfloat16* __restrict__ XL, const __hip_bfloat16* __restrict__ XR,
    const float* __restrict__ att,
    const int* __restrict__ off, const int* __restrict__ srcs,
    const float* __restrict__ bias, __hip_bfloat16* __restrict__ OUT){
  int wave = threadIdx.x >> 6, lane = threadIdx.x & 63;
  int d = blockIdx.x * 4 + wave;
  if (d >= NNODES) return;

  uint4 xru = *(const uint4*)((const char*)XR + ((size_t)d*CDIM + lane*8)*2);
  float xr[8];
  unpk(xru.x, xr[0], xr[1]); unpk(xru.y, xr[2], xr[3]);
  unpk(xru.z, xr[4], xr[5]); unpk(xru.w, xr[6], xr[7]);
  const float4* atp = (const float4*)(att + lane*8);
  float4 at0 = atp[0], at1 = atp[1];
  float at[8] = {at0.x, at0.y, at0.z, at0.w, at1.x, at1.y, at1.z, at1.w};

  float acc[8];
  #pragma unroll
  for (int j = 0; j < 8; j++) acc[j] = 0.f;
  float den = 0.f;

  int beg = off[d], end = off[d+1];

  auto leaky = [](float m){ return fmaxf(m, 0.2f*m); };

  for (int i = beg; i < end; i += 4){
    int n = end - i;                       // wave-uniform
    int s0 = srcs[i];
    int s1 = n > 1 ? srcs[i+1] : s0;
    int s2 = n > 2 ? srcs[i+2] : s0;
    int s3 = n > 3 ? srcs[i+3] : s0;
    uint4 rw[4];
    rw[0] = *(const uint4*)((const char*)XL + ((size_t)s0*CDIM + lane*8)*2);
    rw[1] = *(const uint4*)((const char*)XL + ((size_t)s1*CDIM + lane*8)*2);
    rw[2] = *(const uint4*)((const char*)XL + ((size_t)s2*CDIM + lane*8)*2);
    rw[3] = *(const uint4*)((const char*)XL + ((size_t)s3*CDIM + lane*8)*2);

    #pragma unroll
    for (int e = 0; e < 4; e++){
      if (e < n){                          // wave-uniform branch
        float xv[8];
        unpk(rw[e].x, xv[0], xv[1]);
        unpk(rw[e].y, xv[2], xv[3]);
        unpk(rw[e].z, xv[4], xv[5]);
        unpk(rw[e].w, xv[6], xv[7]);
        float v = 0.f;
        #pragma unroll
        for (int j = 0; j < 8; j++) v = fmaf(leaky(xv[j] + xr[j]), at[j], v);
        v += __shfl_xor(v, 1); v += __shfl_xor(v, 2); v += __shfl_xor(v, 4);
        float p = expf(v);
        den += p;
        #pragma unroll
        for (int j = 0; j < 8; j++) acc[j] = fmaf(p, xv[j], acc[j]);
      }
    }
  }

  float inv = 1.f / (den + 1e-16f);
  const float4* bp = (const float4*)(bias + (CONCAT ? lane*8 : (lane & 7)*8));

  if (CONCAT){
    float4 b0v = bp[0], b1v = bp[1];
    float bb[8] = {b0v.x, b0v.y, b0v.z, b0v.w, b1v.x, b1v.y, b1v.z, b1v.w};
    PK8 pk;
    #pragma unroll
    for (int j = 0; j < 8; j++)
      pk.h[j] = __float2bfloat16(acc[j]*inv + bb[j]);
    *(uint4*)((char*)OUT + ((size_t)d*CDIM + lane*8)*2) = pk.v;
  } else {
    float r[8];
    #pragma unroll
    for (int j = 0; j < 8; j++) r[j] = acc[j] * inv;
    #pragma unroll
    for (int o = 8; o < 64; o <<= 1)
      #pragma unroll
      for (int j = 0; j < 8; j++) r[j] += __shfl_xor(r[j], o);
    if (lane < 8){
      float4 b0v = bp[0], b1v = bp[1];
      float bb[8] = {b0v.x, b0v.y, b0v.z, b0v.w, b1v.x, b1v.y, b1v.z, b1v.w};
      PK8 pk;
      #pragma unroll
      for (int j = 0; j < 8; j++)
        pk.h[j] = __float2bfloat16(r[j]*0.125f + bb[j]);
      *(uint4*)((char*)OUT + ((size_t)d*FDIM + lane*8)*2) = pk.v;
    }
  }
}

// ---------- GraphNorm + ReLU, single pass: thread t caches its column in registers ----------
__global__ void k_graphnorm_relu(const __hip_bfloat16* __restrict__ X, const float* __restrict__ w,
    const float* __restrict__ b, const float* __restrict__ ms,
    __hip_bfloat16* __restrict__ Y, int C){
  int g = blockIdx.x;
  int c = threadIdx.x;
  const __hip_bfloat16* xg = X + (size_t)g * NG * C + c;
  __hip_bfloat16* yg = Y + (size_t)g * NG * C + c;
  float v[NG];
  float s1 = 0.f, s2 = 0.f;
  #pragma unroll
  for (int i = 0; i < NG; i++){
    v[i] = __bfloat162float(xg[(size_t)i*C]);
    s1 += v[i]; s2 += v[i]*v[i];
  }
  float mean = s1 * (1.f/NG);
  float m = ms[c];
  float var = s2 * (1.f/NG) - 2.f*m*mean*mean + m*m*mean*mean;
  float inv = rsqrtf(var + 1e-5f);
  float ww = w[c], bb = b[c];
  #pragma unroll
  for (int i = 0; i < NG; i++){
    float y = fmaf(ww * (v[i] - m*mean), inv, bb);
    yg[(size_t)i*C] = __float2bfloat16(y > 0.f ? y : 0.f);
  }
}

// ---------- global mean pool + linear [64 -> 2], dtype-flag-aware output ----------
__global__ void k_pool_linear(const __hip_bfloat16* __restrict__ H, const float* __restrict__ Wlin,
    const float* __restrict__ blin, void* out, const int* __restrict__ flag){
  int g = blockIdx.x, c = threadIdx.x;  // 64 threads
  float s = 0.f;
  for (int i = 0; i < NG; i++) s += __bfloat162float(H[(long)(g*NG + i)*FDIM + c]);
  float pooled = s * (1.f/NG);
  float v0 = pooled * Wlin[c*2 + 0];
  float v1 = pooled * Wlin[c*2 + 1];
  #pragma unroll
  for (int o = 32; o; o >>= 1){ v0 += __shfl_down(v0, o); v1 += __shfl_down(v1, o); }
  if (c == 0){
    float o0 = v0 + blin[0], o1 = v1 + blin[1];
    if (*flag){
      ((float*)out)[g*2 + 0] = o0;
      ((float*)out)[g*2 + 1] = o1;
    } else {
      ((__hip_bfloat16*)out)[g*2 + 0] = __float2bfloat16(o0);
      ((__hip_bfloat16*)out)[g*2 + 1] = __float2bfloat16(o1);
    }
  }
}

extern "C" void kernel_launch(void* const* d_in, const int* in_sizes, int n_in,
                              void* d_out, int out_size, void* d_ws, size_t ws_size,
                              hipStream_t stream){
  const int N = NNODES;
  const int E = in_sizes[1];

  const int* esrc = (const int*)d_in[1];
  const int* edst = (const int*)d_in[2];

  // ---- workspace layout ----
  char* ws = (char*)d_ws;
  size_t cursor_b = 0;
  auto alloc = [&](size_t bytes)->char*{
    char* p = ws + cursor_b;
    cursor_b += (bytes + 255) & ~size_t(255);
    return p;
  };

  int* flag = (int*)alloc(256);

  // small segments only: att1,b1,gnw1,gnb1,gnm1, att2.., att3.., Wlin, blin
  static const int convIdx[17] = {6,7,8,9,10, 13,14,15,16,17, 20,21,22,23,24, 25,26};
  CArgs ca;
  int cums[18]; cums[0] = 0;
  for (int i = 0; i < 17; i++){
    ca.p[i] = d_in[convIdx[i]];
    cums[i+1] = cums[i] + in_sizes[convIdx[i]];
  }
  memcpy(ca.cum, cums, sizeof(cums));
  int totalConv = cums[17];

  float* conv = (float*)alloc((size_t)totalConv * 4);
  const float* fw[17];
  for (int i = 0; i < 17; i++) fw[i] = conv + cums[i];
  // fw map: 0:att1 1:b1 2:gnw1 3:gnb1 4:gnm1
  //         5:att2 6:b2 7:gnw2 8:gnb2 9:gnm2
  //         10:att3 11:b3 12:gnw3 13:gnb3 14:gnm3 15:Wlin 16:blin

  __hip_bfloat16* XLbf  = (__hip_bfloat16*)alloc((size_t)N * CDIM * 2);
  __hip_bfloat16* XRbf  = (__hip_bfloat16*)alloc((size_t)N * CDIM * 2);
  __hip_bfloat16* OUTbf = (__hip_bfloat16*)alloc((size_t)N * CDIM * 2);   // attn out, pre-norm
  __hip_bfloat16* OUT3  = (__hip_bfloat16*)alloc((size_t)N * FDIM * 2);
  __hip_bfloat16* HBbf  = (__hip_bfloat16*)alloc((size_t)N * CDIM * 2);
  __hip_bfloat16* xbf   = (__hip_bfloat16*)alloc((size_t)N * GIN * 2);
  __hip_bfloat16* Wt[6];
  Wt[0] = (__hip_bfloat16*)alloc((size_t)CDIM * GIN * 2);
  Wt[1] = (__hip_bfloat16*)alloc((size_t)CDIM * GIN * 2);
  Wt[2] = (__hip_bfloat16*)alloc((size_t)CDIM * CDIM * 2);
  Wt[3] = (__hip_bfloat16*)alloc((size_t)CDIM * CDIM * 2);
  Wt[4] = (__hip_bfloat16*)alloc((size_t)CDIM * CDIM * 2);
  Wt[5] = (__hip_bfloat16*)alloc((size_t)CDIM * CDIM * 2);
  int* deg  = (int*)alloc((size_t)N * 4);
  int* off  = (int*)alloc((size_t)(N + 1) * 4);
  int* cur  = (int*)alloc((size_t)N * 4);
  int* srcs = (int*)alloc((size_t)E * 4);

  // ---- dtype detect + convert (+ deg zero) ----
  k_detect<<<1, 64, 0, stream>>>((const unsigned short*)d_in[0], flag);
  k_convert<<<32, 256, 0, stream>>>(ca, flag, conv, totalConv);
  k_xconv<<<2048, 256, 0, stream>>>(d_in[0], flag, xbf, deg, N * GIN);
  {
    TArgs ta;
    const void* Ws[6] = {d_in[4], d_in[5], d_in[11], d_in[12], d_in[18], d_in[19]};
    const int   Ks[6] = {GIN, GIN, CDIM, CDIM, CDIM, CDIM};
    for (int i = 0; i < 6; i++){ ta.W[i] = Ws[i]; ta.Wt[i] = Wt[i]; ta.K[i] = Ks[i]; }
    k_transpose_all<<<dim3(CDIM/32, CDIM/32, 6), dim3(32, 8), 0, stream>>>(ta, flag);
  }

  // ---- CSR by dst (payload = src) ----
  k_count<<<(E + 255)/256, 256, 0, stream>>>(edst, E, deg);
  k_scan<<<1, 256, 0, stream>>>(deg, off, cur);
  k_fill<<<(E + 255)/256, 256, 0, stream>>>(esrc, edst, E, cur, srcs);

  // ---- 3 GATv2 + GraphNorm + ReLU layers ----
  const float* att_[3] = {fw[0],  fw[5],  fw[10]};
  const float* b_[3]   = {fw[1],  fw[6],  fw[11]};
  const float* gw_[3]  = {fw[2],  fw[7],  fw[12]};
  const float* gb_[3]  = {fw[3],  fw[8],  fw[13]};
  const float* gm_[3]  = {fw[4],  fw[9],  fw[14]};

  const __hip_bfloat16* inbuf = xbf;
  int K = GIN;
  for (int layer = 0; layer < 3; layer++){
    k_gemm_mfma<<<dim3(N/128, CDIM/128, 2), 256, 0, stream>>>(
        inbuf, Wt[layer*2], Wt[layer*2 + 1], XLbf, XRbf, K);
    if (layer < 2){
      k_fused_attn<1><<<N/4, 256, 0, stream>>>(XLbf, XRbf, att_[layer], off, srcs, b_[layer], OUTbf);
      k_graphnorm_relu<<<NGRAPH, CDIM, 0, stream>>>(OUTbf, gw_[layer], gb_[layer], gm_[layer], HBbf, CDIM);
    } else {
      k_fused_attn<0><<<N/4, 256, 0, stream>>>(XLbf, XRbf, att_[layer], off, srcs, b_[layer], OUT3);
      k_graphnorm_relu<<<NGRAPH, FDIM, 0, stream>>>(OUT3, gw_[layer], gb_[layer], gm_[layer], HBbf, FDIM);
    }
    inbuf = HBbf;
    K = CDIM;
  }

  // ---- pool + linear ----
  k_pool_linear<<<NGRAPH, 64, 0, stream>>>(HBbf, fw[15], fw[16], d_out, flag);
}